// Round 1
// baseline (458.370 us; speedup 1.0000x reference)
//
#include <hip/hip_runtime.h>
#include <math.h>

// Problem constants (fixed by the reference setup)
#define NTOT 32768
#define NB   64
#define NPB  512      // rows per segment
#define DQK  128
#define MF   256      // feature count m
#define DVV  256      // value dim

#define QK_SCALE   0.29730177875068026f   // 128^-0.25
#define INV_SQRT_M 0.0625f                // 1/sqrt(256)
#define EPS_PHI    1e-4f
#define EPS_NORM   1e-8f

static __device__ __forceinline__ float red_max32(float v) {
    v = fmaxf(v, __shfl_xor(v, 1, 64));
    v = fmaxf(v, __shfl_xor(v, 2, 64));
    v = fmaxf(v, __shfl_xor(v, 4, 64));
    v = fmaxf(v, __shfl_xor(v, 8, 64));
    v = fmaxf(v, __shfl_xor(v, 16, 64));
    return v;
}
static __device__ __forceinline__ float red_sum32(float v) {
    v += __shfl_xor(v, 1, 64);
    v += __shfl_xor(v, 2, 64);
    v += __shfl_xor(v, 4, 64);
    v += __shfl_xor(v, 8, 64);
    v += __shfl_xor(v, 16, 64);
    return v;
}

// ---------------------------------------------------------------------------
// Kernel 1: U = (X * d^-1/4) @ omega  [32 rows/block, all 256 cols]
//   IS_QUERY: out = Qp = (exp(U - h - rowmax(U)) + eps)/sqrt(m)
//   else:     out = U - h   (store), rmax[row] = rowmax(U)
// Block: 256 threads = 8 ty (4 rows each) x 32 tx (8 cols each).
// ---------------------------------------------------------------------------
template <bool IS_QUERY>
__global__ __launch_bounds__(256) void phi_kernel(
    const float* __restrict__ X, const float* __restrict__ omega,
    float* __restrict__ out, float* __restrict__ rmax)
{
    __shared__ __align__(16) float xs[32][132];   // padded: stride 132 breaks k%32 banking
    __shared__ __align__(16) float oms[16][256];

    const int tid = threadIdx.x;
    const int tx  = tid & 31;   // cols tx*8 .. +8
    const int ty  = tid >> 5;   // rows ty*4 .. +4
    const int row0 = blockIdx.x * 32;

    // ---- load X tile (32x128), scaled ----
    {
        const float4* Xv = (const float4*)(X + (size_t)row0 * DQK);
        #pragma unroll
        for (int j = 0; j < 4; ++j) {
            int idx = tid + 256 * j;        // 0..1023 float4s
            int r = idx >> 5;               // 32 float4 per row
            int c = (idx & 31) * 4;
            float4 v = Xv[idx];
            v.x *= QK_SCALE; v.y *= QK_SCALE; v.z *= QK_SCALE; v.w *= QK_SCALE;
            *(float4*)&xs[r][c] = v;
        }
    }
    __syncthreads();

    // ---- h per row: 0.5 * sum(xs^2)  (== sum(x^2)/(2*sqrt(d)) exactly) ----
    float h[4];
    #pragma unroll
    for (int i = 0; i < 4; ++i) {
        float4 v = *(const float4*)&xs[ty * 4 + i][tx * 4];
        float s = v.x * v.x + v.y * v.y + v.z * v.z + v.w * v.w;
        h[i] = 0.5f * red_sum32(s);
    }

    // ---- main GEMM: acc[4 rows][8 cols] ----
    float acc[4][8];
    #pragma unroll
    for (int i = 0; i < 4; ++i)
        #pragma unroll
        for (int j = 0; j < 8; ++j) acc[i][j] = 0.f;

    for (int kc = 0; kc < DQK; kc += 16) {
        __syncthreads();
        // stage omega[kc..kc+16][0..256] -> LDS
        const float4* Ov = (const float4*)(omega + (size_t)kc * MF);
        #pragma unroll
        for (int j = 0; j < 4; ++j) {
            int idx = tid + 256 * j;        // 0..1023 float4s
            int r = idx >> 6;               // 64 float4 per row
            int c = (idx & 63) * 4;
            *(float4*)&oms[r][c] = Ov[idx];
        }
        __syncthreads();

        #pragma unroll
        for (int kk = 0; kk < 16; ++kk) {
            const int k = kc + kk;
            float a0 = xs[ty * 4 + 0][k];
            float a1 = xs[ty * 4 + 1][k];
            float a2 = xs[ty * 4 + 2][k];
            float a3 = xs[ty * 4 + 3][k];
            float4 b0 = *(const float4*)&oms[kk][tx * 8];
            float4 b1 = *(const float4*)&oms[kk][tx * 8 + 4];
            float bb[8] = {b0.x, b0.y, b0.z, b0.w, b1.x, b1.y, b1.z, b1.w};
            #pragma unroll
            for (int j = 0; j < 8; ++j) {
                acc[0][j] = fmaf(a0, bb[j], acc[0][j]);
                acc[1][j] = fmaf(a1, bb[j], acc[1][j]);
                acc[2][j] = fmaf(a2, bb[j], acc[2][j]);
                acc[3][j] = fmaf(a3, bb[j], acc[3][j]);
            }
        }
    }

    // ---- epilogue ----
    #pragma unroll
    for (int i = 0; i < 4; ++i) {
        const int grow = row0 + ty * 4 + i;
        float m = acc[i][0];
        #pragma unroll
        for (int j = 1; j < 8; ++j) m = fmaxf(m, acc[i][j]);
        m = red_max32(m);                    // rowmax of U over all 256 cols

        float4 o0, o1;
        if (IS_QUERY) {
            float hm = h[i] + m;
            o0.x = (__expf(acc[i][0] - hm) + EPS_PHI) * INV_SQRT_M;
            o0.y = (__expf(acc[i][1] - hm) + EPS_PHI) * INV_SQRT_M;
            o0.z = (__expf(acc[i][2] - hm) + EPS_PHI) * INV_SQRT_M;
            o0.w = (__expf(acc[i][3] - hm) + EPS_PHI) * INV_SQRT_M;
            o1.x = (__expf(acc[i][4] - hm) + EPS_PHI) * INV_SQRT_M;
            o1.y = (__expf(acc[i][5] - hm) + EPS_PHI) * INV_SQRT_M;
            o1.z = (__expf(acc[i][6] - hm) + EPS_PHI) * INV_SQRT_M;
            o1.w = (__expf(acc[i][7] - hm) + EPS_PHI) * INV_SQRT_M;
        } else {
            o0.x = acc[i][0] - h[i]; o0.y = acc[i][1] - h[i];
            o0.z = acc[i][2] - h[i]; o0.w = acc[i][3] - h[i];
            o1.x = acc[i][4] - h[i]; o1.y = acc[i][5] - h[i];
            o1.z = acc[i][6] - h[i]; o1.w = acc[i][7] - h[i];
            if (tx == 0) rmax[grow] = m;     // max of U (before h subtraction)
        }
        *(float4*)&out[(size_t)grow * MF + tx * 8]     = o0;
        *(float4*)&out[(size_t)grow * MF + tx * 8 + 4] = o1;
    }
}

// ---------------------------------------------------------------------------
// Kernel 2: segmax[b] = max over 512 rows of rmax
// ---------------------------------------------------------------------------
__global__ __launch_bounds__(256) void segmax_kernel(
    const float* __restrict__ rmax, float* __restrict__ segmax)
{
    const int b = blockIdx.x, tid = threadIdx.x;
    float v = fmaxf(rmax[b * NPB + tid], rmax[b * NPB + 256 + tid]);
    v = red_max32(v);
    v = fmaxf(v, __shfl_xor(v, 32, 64));
    __shared__ float red[4];
    if ((tid & 63) == 0) red[tid >> 6] = v;
    __syncthreads();
    if (tid == 0)
        segmax[b] = fmaxf(fmaxf(red[0], red[1]), fmaxf(red[2], red[3]));
}

// ---------------------------------------------------------------------------
// Kernel 3: KV[b] = Kp_b^T @ V_b  (64x64 tile, 4x4 micro, k-chunk 32 over n=512)
//           Kp computed on the fly from A = U_K - h and segmax.
//           v-tile 0 also produces Ksum[b][m] (column sums of Kp).
// ---------------------------------------------------------------------------
__global__ __launch_bounds__(256) void kv_kernel(
    const float* __restrict__ A, const float* __restrict__ V,
    const float* __restrict__ segmax,
    float* __restrict__ KV, float* __restrict__ Ksum)
{
    const int vt = blockIdx.x, mt = blockIdx.y, b = blockIdx.z;
    const int tid = threadIdx.x;
    const int tx = tid & 15, ty = tid >> 4;
    const int m0 = mt * 64, v0 = vt * 64;
    const int n0 = b * NPB;

    __shared__ __align__(16) float Kps[32][64];  // k-major
    __shared__ __align__(16) float Vs[32][64];

    const float smax = segmax[b];
    float acc[4][4] = {};
    float ks = 0.f;

    const int lr = tid >> 4;          // 0..15 load row
    const int lc = (tid & 15) * 4;    // load col

    for (int nc = 0; nc < NPB; nc += 32) {
        #pragma unroll
        for (int rr = 0; rr < 32; rr += 16) {
            const size_t grow = (size_t)(n0 + nc + lr + rr);
            float4 a = *(const float4*)&A[grow * MF + m0 + lc];
            float4 kp;
            kp.x = (__expf(a.x - smax) + EPS_PHI) * INV_SQRT_M;
            kp.y = (__expf(a.y - smax) + EPS_PHI) * INV_SQRT_M;
            kp.z = (__expf(a.z - smax) + EPS_PHI) * INV_SQRT_M;
            kp.w = (__expf(a.w - smax) + EPS_PHI) * INV_SQRT_M;
            *(float4*)&Kps[lr + rr][lc] = kp;
            *(float4*)&Vs[lr + rr][lc] =
                *(const float4*)&V[grow * DVV + v0 + lc];
        }
        __syncthreads();

        #pragma unroll
        for (int kk = 0; kk < 32; ++kk) {
            float4 a4 = *(const float4*)&Kps[kk][ty * 4];
            float4 b4 = *(const float4*)&Vs[kk][tx * 4];
            float aa[4] = {a4.x, a4.y, a4.z, a4.w};
            float bbv[4] = {b4.x, b4.y, b4.z, b4.w};
            #pragma unroll
            for (int i = 0; i < 4; ++i)
                #pragma unroll
                for (int j = 0; j < 4; ++j)
                    acc[i][j] = fmaf(aa[i], bbv[j], acc[i][j]);
        }
        if (vt == 0 && tid < 64) {
            #pragma unroll
            for (int kk = 0; kk < 32; ++kk) ks += Kps[kk][tid];
        }
        __syncthreads();
    }

    #pragma unroll
    for (int i = 0; i < 4; ++i) {
        float4 o = {acc[i][0], acc[i][1], acc[i][2], acc[i][3]};
        *(float4*)&KV[((size_t)b * MF + m0 + ty * 4 + i) * DVV + v0 + tx * 4] = o;
    }
    if (vt == 0 && tid < 64) Ksum[b * MF + m0 + tid] = ks;
}

// ---------------------------------------------------------------------------
// Kernel 4: out = (Qp @ KV[b]) / (Qp . Ksum[b] + eps)
//           64 rows x 64 v-cols per block, 4x4 micro, k-chunk 32 over m=256.
// ---------------------------------------------------------------------------
__global__ __launch_bounds__(256) void out_kernel(
    const float* __restrict__ Qp, const float* __restrict__ KV,
    const float* __restrict__ Ksum, float* __restrict__ out)
{
    const int vt = blockIdx.x, rt = blockIdx.y, b = blockIdx.z;
    const int tid = threadIdx.x;
    const int tx = tid & 15, ty = tid >> 4;
    const int v0 = vt * 64;
    const int r0 = b * NPB + rt * 64;

    __shared__ __align__(16) float Qs[64][36];   // row-major, padded
    __shared__ __align__(16) float KVs[32][64];  // k-major
    __shared__ __align__(16) float KsS[32];
    __shared__ __align__(16) float nrm[64];

    float acc[4][4] = {};
    float nacc = 0.f;

    const int qr = tid >> 3;          // 0..31
    const int qc = (tid & 7) * 4;
    const int km = tid >> 4;          // 0..15
    const int kc2 = (tid & 15) * 4;

    for (int mc = 0; mc < MF; mc += 32) {
        #pragma unroll
        for (int rr = 0; rr < 64; rr += 32)
            *(float4*)&Qs[qr + rr][qc] =
                *(const float4*)&Qp[(size_t)(r0 + qr + rr) * MF + mc + qc];
        #pragma unroll
        for (int mm = 0; mm < 32; mm += 16)
            *(float4*)&KVs[km + mm][kc2] =
                *(const float4*)&KV[((size_t)b * MF + mc + km + mm) * DVV + v0 + kc2];
        if (tid < 32) KsS[tid] = Ksum[b * MF + mc + tid];
        __syncthreads();

        #pragma unroll
        for (int kk = 0; kk < 32; kk += 2) {
            float2 a2[4];
            #pragma unroll
            for (int i = 0; i < 4; ++i)
                a2[i] = *(const float2*)&Qs[ty * 4 + i][kk];
            float4 b0 = *(const float4*)&KVs[kk][tx * 4];
            float4 b1 = *(const float4*)&KVs[kk + 1][tx * 4];
            float bb0[4] = {b0.x, b0.y, b0.z, b0.w};
            float bb1[4] = {b1.x, b1.y, b1.z, b1.w};
            #pragma unroll
            for (int i = 0; i < 4; ++i)
                #pragma unroll
                for (int j = 0; j < 4; ++j) {
                    acc[i][j] = fmaf(a2[i].x, bb0[j], acc[i][j]);
                    acc[i][j] = fmaf(a2[i].y, bb1[j], acc[i][j]);
                }
        }
        if (tid < 64) {      // norm partial for row tid
            #pragma unroll
            for (int c4 = 0; c4 < 8; ++c4) {
                float4 q = *(const float4*)&Qs[tid][c4 * 4];
                float4 k = *(const float4*)&KsS[c4 * 4];
                nacc += q.x * k.x + q.y * k.y + q.z * k.z + q.w * k.w;
            }
        }
        __syncthreads();
    }

    if (tid < 64) nrm[tid] = nacc;
    __syncthreads();

    #pragma unroll
    for (int i = 0; i < 4; ++i) {
        const float inv = 1.0f / (nrm[ty * 4 + i] + EPS_NORM);
        float4 o = {acc[i][0] * inv, acc[i][1] * inv,
                    acc[i][2] * inv, acc[i][3] * inv};
        *(float4*)&out[(size_t)(r0 + ty * 4 + i) * DVV + v0 + tx * 4] = o;
    }
}

// ---------------------------------------------------------------------------
extern "C" void kernel_launch(void* const* d_in, const int* in_sizes, int n_in,
                              void* d_out, int out_size, void* d_ws, size_t ws_size,
                              hipStream_t stream)
{
    const float* Q     = (const float*)d_in[0];
    const float* K     = (const float*)d_in[1];
    const float* V     = (const float*)d_in[2];
    const float* omega = (const float*)d_in[3];
    float* out = (float*)d_out;

    float* ws    = (float*)d_ws;
    float* Qp    = ws;                              // N*M      = 8,388,608
    float* A     = Qp   + (size_t)NTOT * MF;        // N*M      = 8,388,608
    float* KV    = A    + (size_t)NTOT * MF;        // B*M*DV   = 4,194,304
    float* Ksum  = KV   + (size_t)NB * MF * DVV;    // B*M      = 16,384
    float* rmaxA = Ksum + (size_t)NB * MF;          // N        = 32,768
    float* smax  = rmaxA + NTOT;                    // B        = 64
    // total ~80.2 MiB of f32 workspace

    phi_kernel<true ><<<NTOT / 32, 256, 0, stream>>>(Q, omega, Qp, nullptr);
    phi_kernel<false><<<NTOT / 32, 256, 0, stream>>>(K, omega, A, rmaxA);
    segmax_kernel<<<NB, 256, 0, stream>>>(rmaxA, smax);
    kv_kernel<<<dim3(4, 4, NB), 256, 0, stream>>>(A, V, smax, KV, Ksum);
    out_kernel<<<dim3(4, 8, NB), 256, 0, stream>>>(Qp, KV, Ksum, out);
}

// Round 2
// 357.921 us; speedup vs baseline: 1.2806x; 1.2806x over previous
//
#include <hip/hip_runtime.h>
#include <math.h>

// Problem constants (fixed by the reference setup)
#define NTOT 32768
#define NB   64
#define NPB  512      // rows per segment
#define DQK  128
#define MF   256      // feature count m
#define DVV  256      // value dim

#define QK_SCALE   0.29730177875068026f   // 128^-0.25
#define INV_SQRT_M 0.0625f                // 1/sqrt(256)
#define EPS_PHI    1e-4f
#define EPS_NORM   1e-8f

static __device__ __forceinline__ float red_max32(float v) {
    v = fmaxf(v, __shfl_xor(v, 1, 64));
    v = fmaxf(v, __shfl_xor(v, 2, 64));
    v = fmaxf(v, __shfl_xor(v, 4, 64));
    v = fmaxf(v, __shfl_xor(v, 8, 64));
    v = fmaxf(v, __shfl_xor(v, 16, 64));
    return v;
}
static __device__ __forceinline__ float red_sum32(float v) {
    v += __shfl_xor(v, 1, 64);
    v += __shfl_xor(v, 2, 64);
    v += __shfl_xor(v, 4, 64);
    v += __shfl_xor(v, 8, 64);
    v += __shfl_xor(v, 16, 64);
    return v;
}

// ---------------------------------------------------------------------------
// Kernel 1: U = (X * d^-1/4) @ omega  [64 rows x all 256 cols per block]
// 256 threads: tx = tid&31 (8 cols each), ty = tid>>5 (8 rows each). 8x8 micro.
//   IS_QUERY: out = Qp = (exp(U - h - rowmax)+eps)/sqrt(m); aux = norm = Qp.Ksum[seg]
//   else:     out = U - h; aux = rowmax(U)
// X tile staged row-major in LDS; A-frag read as float4 along k (held 4 steps).
// ---------------------------------------------------------------------------
template <bool IS_QUERY>
__global__ __launch_bounds__(256) void phi_kernel(
    const float* __restrict__ X, const float* __restrict__ omega,
    const float* __restrict__ Ksum,
    float* __restrict__ out, float* __restrict__ aux)
{
    __shared__ __align__(16) float xs[64][132];   // row-major, stride%32==4 -> uniform banks
    __shared__ __align__(16) float oms[16][256];  // k-major omega chunk
    __shared__ float KsS[256];

    const int tid = threadIdx.x;
    const int tx  = tid & 31;
    const int ty  = tid >> 5;
    const int row0 = blockIdx.x * 64;

    if (IS_QUERY) KsS[tid] = Ksum[(row0 >> 9) * MF + tid];

    // ---- stage X tile (64x128), scaled, row-major ----
    {
        const float4* Xv = (const float4*)(X + (size_t)row0 * DQK);
        #pragma unroll
        for (int j = 0; j < 8; ++j) {             // 2048 float4 / 256 thr
            int idx = tid + 256 * j;
            int r = idx >> 5, c4 = idx & 31;
            float4 v = Xv[idx];
            v.x *= QK_SCALE; v.y *= QK_SCALE; v.z *= QK_SCALE; v.w *= QK_SCALE;
            *(float4*)&xs[r][c4 * 4] = v;
        }
    }

    float acc[8][8] = {};
    float h[8] = {};

    // prefetch omega chunk 0 (16 k-rows x 256)
    const float4* Ov = (const float4*)omega;
    float4 oreg[4];
    #pragma unroll
    for (int j = 0; j < 4; ++j) oreg[j] = Ov[tid + 256 * j];

    for (int c = 0; c < 8; ++c) {
        __syncthreads();
        #pragma unroll
        for (int j = 0; j < 4; ++j) {
            int idx = tid + 256 * j;
            *(float4*)&oms[idx >> 6][(idx & 63) * 4] = oreg[j];
        }
        __syncthreads();
        if (c < 7) {
            #pragma unroll
            for (int j = 0; j < 4; ++j)
                oreg[j] = Ov[(c + 1) * 1024 + tid + 256 * j];
        }
        const int kc = c * 16;
        #pragma unroll
        for (int kq = 0; kq < 4; ++kq) {
            float4 a4[8];
            #pragma unroll
            for (int i = 0; i < 8; ++i)
                a4[i] = *(const float4*)&xs[ty * 8 + i][kc + kq * 4];
            #pragma unroll
            for (int t = 0; t < 4; ++t) {
                const int kk = kq * 4 + t;
                float4 b0 = *(const float4*)&oms[kk][tx * 8];
                float4 b1 = *(const float4*)&oms[kk][tx * 8 + 4];
                float bv[8] = {b0.x, b0.y, b0.z, b0.w, b1.x, b1.y, b1.z, b1.w};
                #pragma unroll
                for (int i = 0; i < 8; ++i) {
                    const float av = ((const float*)&a4[i])[t];
                    h[i] = fmaf(av, av, h[i]);
                    #pragma unroll
                    for (int j = 0; j < 8; ++j)
                        acc[i][j] = fmaf(av, bv[j], acc[i][j]);
                }
            }
        }
    }

    // ---- epilogue ----
    #pragma unroll
    for (int i = 0; i < 8; ++i) {
        const int grow = row0 + ty * 8 + i;
        float mx = acc[i][0];
        #pragma unroll
        for (int j = 1; j < 8; ++j) mx = fmaxf(mx, acc[i][j]);
        mx = red_max32(mx);
        const float hv = 0.5f * h[i];

        if (IS_QUERY) {
            const float hm = hv + mx;
            float q[8];
            #pragma unroll
            for (int j = 0; j < 8; ++j)
                q[j] = (__expf(acc[i][j] - hm) + EPS_PHI) * INV_SQRT_M;
            float4 o0 = {q[0], q[1], q[2], q[3]};
            float4 o1 = {q[4], q[5], q[6], q[7]};
            *(float4*)&out[(size_t)grow * MF + tx * 8]     = o0;
            *(float4*)&out[(size_t)grow * MF + tx * 8 + 4] = o1;
            float np = 0.f;
            #pragma unroll
            for (int j = 0; j < 8; ++j) np = fmaf(q[j], KsS[tx * 8 + j], np);
            np = red_sum32(np);
            if (tx == 0) aux[grow] = np;
        } else {
            float4 o0 = {acc[i][0] - hv, acc[i][1] - hv, acc[i][2] - hv, acc[i][3] - hv};
            float4 o1 = {acc[i][4] - hv, acc[i][5] - hv, acc[i][6] - hv, acc[i][7] - hv};
            *(float4*)&out[(size_t)grow * MF + tx * 8]     = o0;
            *(float4*)&out[(size_t)grow * MF + tx * 8 + 4] = o1;
            if (tx == 0) aux[grow] = mx;
        }
    }
}

// ---------------------------------------------------------------------------
// Kernel 2: segmax[b] = max over 512 rows of rmax
// ---------------------------------------------------------------------------
__global__ __launch_bounds__(256) void segmax_kernel(
    const float* __restrict__ rmax, float* __restrict__ segmax)
{
    const int b = blockIdx.x, tid = threadIdx.x;
    float v = fmaxf(rmax[b * NPB + tid], rmax[b * NPB + 256 + tid]);
    v = red_max32(v);
    v = fmaxf(v, __shfl_xor(v, 32, 64));
    __shared__ float red[4];
    if ((tid & 63) == 0) red[tid >> 6] = v;
    __syncthreads();
    if (tid == 0)
        segmax[b] = fmaxf(fmaxf(red[0], red[1]), fmaxf(red[2], red[3]));
}

// ---------------------------------------------------------------------------
// Kernel 3: KV[b] = Kp_b^T @ V_b. 128x128 tile, 8x8 micro, n-chunk 32,
// register-prefetch pipeline. Kp = exp(A - segmax) applied at LDS-write time.
// vt==0 blocks also emit Ksum via per-thread register partials (each thread's
// staged float4s share the same m-columns across all chunks).
// ---------------------------------------------------------------------------
__global__ __launch_bounds__(256) void kv_kernel(
    const float* __restrict__ A, const float* __restrict__ V,
    const float* __restrict__ segmax,
    float* __restrict__ KV, float* __restrict__ Ksum)
{
    __shared__ __align__(16) float Kps[32][128];
    __shared__ __align__(16) float Vs[32][128];

    const int tid = threadIdx.x;
    const int tx = tid & 15, ty = tid >> 4;
    const int vt = blockIdx.x, mt = blockIdx.y, b = blockIdx.z;
    const int m0 = mt * 128, v0 = vt * 128;
    const size_t n0 = (size_t)b * NPB;
    const float smax = segmax[b];

    const int ln  = tid >> 5;     // 0..7  (n within chunk, +8j)
    const int lm4 = tid & 31;     // float4 column

    float acc[8][8] = {};
    float4 ks4 = {0.f, 0.f, 0.f, 0.f};

    float4 areg[4], vreg[4];
    #pragma unroll
    for (int j = 0; j < 4; ++j) {
        const size_t n = n0 + ln + 8 * j;
        areg[j] = *(const float4*)&A[n * MF + m0 + lm4 * 4];
        vreg[j] = *(const float4*)&V[n * DVV + v0 + lm4 * 4];
    }

    for (int c = 0; c < 16; ++c) {
        __syncthreads();
        #pragma unroll
        for (int j = 0; j < 4; ++j) {
            float4 e;
            e.x = (__expf(areg[j].x - smax) + EPS_PHI) * INV_SQRT_M;
            e.y = (__expf(areg[j].y - smax) + EPS_PHI) * INV_SQRT_M;
            e.z = (__expf(areg[j].z - smax) + EPS_PHI) * INV_SQRT_M;
            e.w = (__expf(areg[j].w - smax) + EPS_PHI) * INV_SQRT_M;
            ks4.x += e.x; ks4.y += e.y; ks4.z += e.z; ks4.w += e.w;
            *(float4*)&Kps[ln + 8 * j][lm4 * 4] = e;
            *(float4*)&Vs[ln + 8 * j][lm4 * 4]  = vreg[j];
        }
        __syncthreads();
        if (c < 15) {
            #pragma unroll
            for (int j = 0; j < 4; ++j) {
                const size_t n = n0 + (c + 1) * 32 + ln + 8 * j;
                areg[j] = *(const float4*)&A[n * MF + m0 + lm4 * 4];
                vreg[j] = *(const float4*)&V[n * DVV + v0 + lm4 * 4];
            }
        }
        #pragma unroll 8
        for (int kk = 0; kk < 32; ++kk) {
            float4 a0 = *(const float4*)&Kps[kk][ty * 8];
            float4 a1 = *(const float4*)&Kps[kk][ty * 8 + 4];
            float4 b0 = *(const float4*)&Vs[kk][tx * 8];
            float4 b1 = *(const float4*)&Vs[kk][tx * 8 + 4];
            float av[8] = {a0.x, a0.y, a0.z, a0.w, a1.x, a1.y, a1.z, a1.w};
            float bv[8] = {b0.x, b0.y, b0.z, b0.w, b1.x, b1.y, b1.z, b1.w};
            #pragma unroll
            for (int i = 0; i < 8; ++i)
                #pragma unroll
                for (int j = 0; j < 8; ++j)
                    acc[i][j] = fmaf(av[i], bv[j], acc[i][j]);
        }
    }

    #pragma unroll
    for (int i = 0; i < 8; ++i) {
        float4 o0 = {acc[i][0], acc[i][1], acc[i][2], acc[i][3]};
        float4 o1 = {acc[i][4], acc[i][5], acc[i][6], acc[i][7]};
        const size_t base = ((size_t)b * MF + m0 + ty * 8 + i) * DVV + v0 + tx * 8;
        *(float4*)&KV[base]     = o0;
        *(float4*)&KV[base + 4] = o1;
    }

    if (vt == 0) {
        __syncthreads();                       // compute reads of Kps done
        *(float4*)&Kps[ln][lm4 * 4] = ks4;     // scratch [8][128]
        __syncthreads();
        if (tid < 128) {
            float s = 0.f;
            #pragma unroll
            for (int g = 0; g < 8; ++g) s += Kps[g][tid];
            Ksum[b * MF + m0 + tid] = s;
        }
    }
}

// ---------------------------------------------------------------------------
// Kernel 4: out = (Qp @ KV[b]) / (norm + eps). 128 rows x 128 v per block,
// 8x8 micro, m-chunk 32, register-prefetch pipeline. Qp kept row-major in
// LDS; A-frag read as float4 along k (held across 4 k-steps).
// ---------------------------------------------------------------------------
__global__ __launch_bounds__(256) void out_kernel(
    const float* __restrict__ Qp, const float* __restrict__ KVm,
    const float* __restrict__ normv, float* __restrict__ out)
{
    __shared__ __align__(16) float Qs[128][36];   // row-major, stride%32==4
    __shared__ __align__(16) float KVs[32][128];  // k-major
    __shared__ float nrmS[128];

    const int tid = threadIdx.x;
    const int tx = tid & 15, ty = tid >> 4;
    const int vt = blockIdx.x, rt = blockIdx.y, b = blockIdx.z;
    const int v0 = vt * 128;
    const int r0 = b * NPB + rt * 128;

    if (tid < 128) nrmS[tid] = normv[r0 + tid];

    const int qr  = tid >> 3;     // 0..31 (+32j)
    const int qm4 = tid & 7;
    const int km  = tid >> 5;     // 0..7  (+8j)
    const int kv4 = tid & 31;

    float acc[8][8] = {};

    float4 qreg[4], kreg[4];
    #pragma unroll
    for (int j = 0; j < 4; ++j) {
        qreg[j] = *(const float4*)&Qp[(size_t)(r0 + qr + 32 * j) * MF + qm4 * 4];
        kreg[j] = *(const float4*)&KVm[((size_t)b * MF + km + 8 * j) * DVV + v0 + kv4 * 4];
    }

    for (int c = 0; c < 8; ++c) {
        __syncthreads();
        #pragma unroll
        for (int j = 0; j < 4; ++j) {
            *(float4*)&Qs[qr + 32 * j][qm4 * 4]  = qreg[j];
            *(float4*)&KVs[km + 8 * j][kv4 * 4] = kreg[j];
        }
        __syncthreads();
        if (c < 7) {
            const int mc = (c + 1) * 32;
            #pragma unroll
            for (int j = 0; j < 4; ++j) {
                qreg[j] = *(const float4*)&Qp[(size_t)(r0 + qr + 32 * j) * MF + mc + qm4 * 4];
                kreg[j] = *(const float4*)&KVm[((size_t)b * MF + mc + km + 8 * j) * DVV + v0 + kv4 * 4];
            }
        }
        #pragma unroll 2
        for (int kq = 0; kq < 8; ++kq) {
            float4 a4[8];
            #pragma unroll
            for (int i = 0; i < 8; ++i)
                a4[i] = *(const float4*)&Qs[ty * 8 + i][kq * 4];
            #pragma unroll
            for (int t = 0; t < 4; ++t) {
                const int kk = kq * 4 + t;
                float4 b0 = *(const float4*)&KVs[kk][tx * 8];
                float4 b1 = *(const float4*)&KVs[kk][tx * 8 + 4];
                float bv[8] = {b0.x, b0.y, b0.z, b0.w, b1.x, b1.y, b1.z, b1.w};
                #pragma unroll
                for (int i = 0; i < 8; ++i) {
                    const float av = ((const float*)&a4[i])[t];
                    #pragma unroll
                    for (int j = 0; j < 8; ++j)
                        acc[i][j] = fmaf(av, bv[j], acc[i][j]);
                }
            }
        }
    }

    #pragma unroll
    for (int i = 0; i < 8; ++i) {
        const float inv = 1.0f / (nrmS[ty * 8 + i] + EPS_NORM);
        float4 o0 = {acc[i][0] * inv, acc[i][1] * inv, acc[i][2] * inv, acc[i][3] * inv};
        float4 o1 = {acc[i][4] * inv, acc[i][5] * inv, acc[i][6] * inv, acc[i][7] * inv};
        const size_t base = (size_t)(r0 + ty * 8 + i) * DVV + v0 + tx * 8;
        *(float4*)&out[base]     = o0;
        *(float4*)&out[base + 4] = o1;
    }
}

// ---------------------------------------------------------------------------
extern "C" void kernel_launch(void* const* d_in, const int* in_sizes, int n_in,
                              void* d_out, int out_size, void* d_ws, size_t ws_size,
                              hipStream_t stream)
{
    const float* Q     = (const float*)d_in[0];
    const float* K     = (const float*)d_in[1];
    const float* V     = (const float*)d_in[2];
    const float* omega = (const float*)d_in[3];
    float* out = (float*)d_out;

    float* ws    = (float*)d_ws;
    float* Qp    = ws;                              // N*M
    float* A     = Qp    + (size_t)NTOT * MF;       // N*M
    float* KV    = A     + (size_t)NTOT * MF;       // B*M*DV
    float* Ksum  = KV    + (size_t)NB * MF * DVV;   // B*M
    float* rmaxA = Ksum  + (size_t)NB * MF;         // N
    float* smax  = rmaxA + NTOT;                    // B
    float* normv = smax  + NB;                      // N

    phi_kernel<false><<<NTOT / 64, 256, 0, stream>>>(K, omega, (const float*)nullptr, A, rmaxA);
    segmax_kernel<<<NB, 256, 0, stream>>>(rmaxA, smax);
    kv_kernel<<<dim3(2, 2, NB), 256, 0, stream>>>(A, V, smax, KV, Ksum);
    phi_kernel<true ><<<NTOT / 64, 256, 0, stream>>>(Q, omega, Ksum, Qp, normv);
    out_kernel<<<dim3(2, 4, NB), 256, 0, stream>>>(Qp, KV, normv, out);
}